// Round 16
// baseline (509.129 us; speedup 1.0000x reference)
//
#include <hip/hip_runtime.h>
#include <hip/hip_bf16.h>
#include <math.h>

// Problem constants (reference: B=64, L=1024, H=64, VOCAB=64)
#define BB 64
#define LL 1024
#define HH 64

typedef float v4f __attribute__((ext_vector_type(4)));
#define F4 __builtin_elementwise_fma

// ---------------------------------------------------------------------------
// Kernel 1: per-token phase (v1, best measured). Unchanged.
// ---------------------------------------------------------------------------
__global__ __launch_bounds__(256, 1)
void token_kernel(const int* __restrict__ seq,
                  const float* __restrict__ embed_W,
                  const float* __restrict__ ff_W1, const float* __restrict__ ff_b1,
                  const float* __restrict__ ff_W2, const float* __restrict__ ff_b2,
                  const float* __restrict__ ln_g, const float* __restrict__ ln_b,
                  const float* __restrict__ kp_W, const float* __restrict__ vp_W,
                  const float* __restrict__ qp_W,
                  float* __restrict__ knv, float* __restrict__ vthr,
                  float* __restrict__ qbuf)
{
    __shared__ __align__(16) float h_s[32][64];    // 8 KB
    __shared__ __align__(16) float t1_s[32][128];  // 16 KB
    __shared__ __align__(16) float hn_s[32][64];   // 8 KB

    const int tid  = threadIdx.x;
    const int tok0 = blockIdx.x * 32;

    // ---- Stage A: embedding gather into LDS ----
#pragma unroll
    for (int k = 0; k < 8; ++k) {
        int e   = k * 256 + tid;
        int tok = e >> 6, i = e & 63;
        int s   = seq[tok0 + tok];
        h_s[tok][i] = embed_W[s * 64 + i];
    }
    __syncthreads();

    // ---- Stage B: FF1 (64 -> 128, ReLU) ----
    {
        const int j = tid & 127;
        const int g = tid >> 7;
        float w1c[64];
#pragma unroll
        for (int ii = 0; ii < 64; ++ii) w1c[ii] = ff_W1[ii * 128 + j];
        const float b1j = ff_b1[j];
#pragma unroll
        for (int tk = 0; tk < 16; ++tk) {
            const int tok = g * 16 + tk;
            const float4* h4 = (const float4*)h_s[tok];
            float a0 = b1j, a1 = 0.f, a2 = 0.f, a3 = 0.f;
#pragma unroll
            for (int w = 0; w < 16; ++w) {
                float4 hv = h4[w];
                a0 = fmaf(hv.x, w1c[4*w+0], a0);
                a1 = fmaf(hv.y, w1c[4*w+1], a1);
                a2 = fmaf(hv.z, w1c[4*w+2], a2);
                a3 = fmaf(hv.w, w1c[4*w+3], a3);
            }
            t1_s[tok][j] = fmaxf((a0 + a1) + (a2 + a3), 0.f);
        }
    }
    __syncthreads();

    // ---- Stage C: FF2 (128 -> 64) + residual + LayerNorm ----
    {
        const int i  = tid & 63;
        const int w4 = tid >> 6;
        const float b2i = ff_b2[i];
        const float gi  = ln_g[i];
        const float bi  = ln_b[i];
        float accf[8];
#pragma unroll
        for (int tk = 0; tk < 8; ++tk) accf[tk] = b2i;
#pragma unroll
        for (int h = 0; h < 2; ++h) {
            float w2c[64];
#pragma unroll
            for (int jj = 0; jj < 64; ++jj) w2c[jj] = ff_W2[(h*64 + jj) * 64 + i];
#pragma unroll
            for (int tk = 0; tk < 8; ++tk) {
                const int tok = w4 * 8 + tk;
                const float4* t4 = (const float4*)&t1_s[tok][h*64];
                float a0 = 0.f, a1 = 0.f, a2 = 0.f, a3 = 0.f;
#pragma unroll
                for (int w = 0; w < 16; ++w) {
                    float4 tv = t4[w];
                    a0 = fmaf(tv.x, w2c[4*w+0], a0);
                    a1 = fmaf(tv.y, w2c[4*w+1], a1);
                    a2 = fmaf(tv.z, w2c[4*w+2], a2);
                    a3 = fmaf(tv.w, w2c[4*w+3], a3);
                }
                accf[tk] += (a0 + a1) + (a2 + a3);
            }
        }
#pragma unroll
        for (int tk = 0; tk < 8; ++tk) {
            const int tok = w4 * 8 + tk;
            float x = h_s[tok][i] + accf[tk];
            float s = x;
#pragma unroll
            for (int m = 32; m > 0; m >>= 1) s += __shfl_xor(s, m);
            float mu = s * (1.f / 64.f);
            float d  = x - mu;
            float s2 = d * d;
#pragma unroll
            for (int m = 32; m > 0; m >>= 1) s2 += __shfl_xor(s2, m);
            float var = s2 * (1.f / 64.f);
            hn_s[tok][i] = d / sqrtf(var + 1e-5f) * gi + bi;
        }
    }
    __syncthreads();

    // ---- Stage D: kn/v into packed stream (t<1023) OR q (t==1023) ----
    {
        const int i  = tid & 63;
        const int w4 = tid >> 6;
        float kc[64], vc[64];
#pragma unroll
        for (int ii = 0; ii < 64; ++ii) {
            kc[ii] = kp_W[ii * 64 + i];
            vc[ii] = vp_W[ii * 64 + i];
        }
#pragma unroll
        for (int tk = 0; tk < 8; ++tk) {
            const int tok = w4 * 8 + tk;
            const int tg  = tok0 + tok;
            const int b   = tg >> 10;
            const int t   = tg & 1023;
            const float4* hn4 = (const float4*)hn_s[tok];
            if (t < 1023) {
                float ka0=0.f,ka1=0.f,ka2=0.f,ka3=0.f;
                float va0=0.f,va1=0.f,va2=0.f,va3=0.f;
#pragma unroll
                for (int w = 0; w < 16; ++w) {
                    float4 hv = hn4[w];
                    ka0 = fmaf(hv.x, kc[4*w+0], ka0);
                    ka1 = fmaf(hv.y, kc[4*w+1], ka1);
                    ka2 = fmaf(hv.z, kc[4*w+2], ka2);
                    ka3 = fmaf(hv.w, kc[4*w+3], ka3);
                    va0 = fmaf(hv.x, vc[4*w+0], va0);
                    va1 = fmaf(hv.y, vc[4*w+1], va1);
                    va2 = fmaf(hv.z, vc[4*w+2], va2);
                    va3 = fmaf(hv.w, vc[4*w+3], va3);
                }
                float ka = (ka0 + ka1) + (ka2 + ka3);
                float va = (va0 + va1) + (va2 + va3);
                float kn2 = ka * ka, vn2 = va * va;
#pragma unroll
                for (int m = 32; m > 0; m >>= 1) {
                    kn2 += __shfl_xor(kn2, m);
                    vn2 += __shfl_xor(vn2, m);
                }
                float knorm = fmaxf(sqrtf(kn2), 1e-12f);
                size_t row = ((size_t)b * 1024 + t) * 128;
                knv[row + i]      = ka / knorm;
                knv[row + 64 + i] = va;
                if (i == 0) vthr[b * 1024 + t] = 0.16f * vn2;   // SQUARED threshold
            } else {
                float qa0=0.f,qa1=0.f,qa2=0.f,qa3=0.f;
#pragma unroll
                for (int w = 0; w < 16; ++w) {
                    float4 hv = hn4[w];
                    qa0 = fmaf(hv.x, qp_W[(4*w+0)*64 + i], qa0);
                    qa1 = fmaf(hv.y, qp_W[(4*w+1)*64 + i], qa1);
                    qa2 = fmaf(hv.z, qp_W[(4*w+2)*64 + i], qa2);
                    qa3 = fmaf(hv.w, qp_W[(4*w+3)*64 + i], qa3);
                }
                qbuf[b * 64 + i] = (qa0 + qa1) + (qa2 + qa3);
            }
        }
    }
}

// ---------------------------------------------------------------------------
// Kernel 2: sequential fast-weight scan + output head.
// TWO INDEPENDENT BATCHES PER BLOCK on the r8 G=2 / 4-wave structure.
// r15 BUGFIX: batch-A and batch-B ring buffers are ONE shared array
// (bufAB[2*6144]); the chunk body's "+6144" batch-B addressing is now
// correct BY CONSTRUCTION (r15 assumed separate __shared__ arrays were
// adjacent -- they were not -> absmax 44).
// Block p handles batches bA=2p, bB=2p+1; every wave carries both chains'
// state, chunk body interleaves them (verbatim r8 expression trees per
// batch -> bit-identical outputs). One barrier + one wsum8 per 4 steps.
// grid = 32, block = 256 (4 waves).
// ---------------------------------------------------------------------------

template<int CTRL>
__device__ __forceinline__ float dppadd(float x) {
    int y = __builtin_amdgcn_update_dpp(0, __float_as_int(x), CTRL, 0xF, 0xF, true);
    return x + __int_as_float(y);
}

__device__ __forceinline__ float bcast63(float x) {
    return __int_as_float(__builtin_amdgcn_readlane(__float_as_int(x), 63));
}

// full-wave (64 lane) sum, result broadcast (prologue use)
__device__ __forceinline__ float wave_sum64(float x) {
    x = dppadd<0x111>(x); x = dppadd<0x112>(x);
    x = dppadd<0x114>(x); x = dppadd<0x118>(x);
    x = dppadd<0x142>(x); x = dppadd<0x143>(x);
    return bcast63(x);
}

// eight independent wave sums, DPP levels interleaved (latency amortized)
__device__ __forceinline__ void wsum8(float& a, float& b, float& c, float& d,
                                      float& e, float& f, float& g, float& h) {
#define LVL(C) a=dppadd<C>(a); b=dppadd<C>(b); c=dppadd<C>(c); d=dppadd<C>(d); \
               e=dppadd<C>(e); f=dppadd<C>(f); g=dppadd<C>(g); h=dppadd<C>(h);
    LVL(0x111) LVL(0x112) LVL(0x114) LVL(0x118) LVL(0x142) LVL(0x143)
#undef LVL
    a=bcast63(a); b=bcast63(b); c=bcast63(c); d=bcast63(d);
    e=bcast63(e); f=bcast63(f); g=bcast63(g); h=bcast63(h);
}

// load this wave's quarter of a kn row into quarter-set P (4 x ds_read_b128)
#define LOADK4(P, ROW) do { \
    const float* r_ = (ROW) + (wid << 4); \
    P##0 = *(const v4f*)(r_ + 0);  P##1 = *(const v4f*)(r_ + 4); \
    P##2 = *(const v4f*)(r_ + 8);  P##3 = *(const v4f*)(r_ + 12); \
} while (0)

// M(quarter) += G * P(quarter)   (branchless; G==0 exact no-op on finite P)
#define UPD4M(M, P, G) do { \
    v4f gv_ = {G, G, G, G}; \
    M##0 = F4(gv_, P##0, M##0); M##1 = F4(gv_, P##1, M##1); \
    M##2 = F4(gv_, P##2, M##2); M##3 = F4(gv_, P##3, M##3); \
} while (0)

// One dual-batch chunk u (steps 2u, 2u+1 of BOTH batches).
// RA2/RA3 = batch-A row pointers (rows 2u+2, 2u+3) inside bufAB[0..6143];
// batch-B rows are at +6144 floats (same array -> guaranteed).
// TPA2/TPA3 = batch-A global th pointers; batch-B th at +1024.
#define CHUNK2AB(UP, UQ, XR, XS, RA2, RA3, TPA2, TPA3, PAR) do { \
    UPD4M(mA, UP##A, gdpA);  UPD4M(mB, UP##B, gdpB); \
    UPD4M(mA, UQ##A, gdqA);  UPD4M(mB, UQ##B, gdqB); \
    v4f qA_ = F4(mA0, XR##A0, F4(mA1, XR##A1, F4(mA2, XR##A2, mA3 * XR##A3))); \
    float own0A_ = (qA_.x + qA_.y) + (qA_.z + qA_.w); \
    v4f rA_ = F4(mA0, XS##A0, F4(mA1, XS##A1, F4(mA2, XS##A2, mA3 * XS##A3))); \
    float own1A_ = (rA_.x + rA_.y) + (rA_.z + rA_.w); \
    v4f qB_ = F4(mB0, XR##B0, F4(mB1, XR##B1, F4(mB2, XR##B2, mB3 * XR##B3))); \
    float own0B_ = (qB_.x + qB_.y) + (qB_.z + qB_.w); \
    v4f rB_ = F4(mB0, XS##B0, F4(mB1, XS##B1, F4(mB2, XS##B2, mB3 * XS##B3))); \
    float own1B_ = (rB_.x + rB_.y) + (rB_.z + rB_.w); \
    ((float2*)pexA[PAR][wid])[lane] = make_float2(own0A_, own1A_); \
    ((float2*)pexB[PAR][wid])[lane] = make_float2(own0B_, own1B_); \
    asm volatile("s_waitcnt lgkmcnt(0)\n\ts_barrier" ::: "memory"); \
    float2 p0A_ = ((const float2*)pexA[PAR][0])[lane]; \
    float2 p1A_ = ((const float2*)pexA[PAR][1])[lane]; \
    float2 p2A_ = ((const float2*)pexA[PAR][2])[lane]; \
    float2 p3A_ = ((const float2*)pexA[PAR][3])[lane]; \
    float2 p0B_ = ((const float2*)pexB[PAR][0])[lane]; \
    float2 p1B_ = ((const float2*)pexB[PAR][1])[lane]; \
    float2 p2B_ = ((const float2*)pexB[PAR][2])[lane]; \
    float2 p3B_ = ((const float2*)pexB[PAR][3])[lane]; \
    float knl2A_ = (RA2)[lane]; \
    float knl3A_ = (RA3)[lane]; \
    float vv2A_  = (RA2)[64 + lane]; \
    float vv3A_  = (RA3)[64 + lane]; \
    float knl2B_ = (RA2)[6144 + lane]; \
    float knl3B_ = (RA3)[6144 + lane]; \
    float vv2B_  = (RA2)[6144 + 64 + lane]; \
    float vv3B_  = (RA3)[6144 + 64 + lane]; \
    float th2A_  = *(TPA2); \
    float th3A_  = *(TPA3); \
    float th2B_  = *((TPA2) + 1024); \
    float th3B_  = *((TPA3) + 1024); \
    LOADK4(UP##A, RA2); \
    LOADK4(UQ##A, RA3); \
    LOADK4(UP##B, (RA2) + 6144); \
    LOADK4(UQ##B, (RA3) + 6144); \
    float base0A_ = (p0A_.x + p1A_.x) + (p2A_.x + p3A_.x); \
    float base1A_ = (p0A_.y + p1A_.y) + (p2A_.y + p3A_.y); \
    float base0B_ = (p0B_.x + p1B_.x) + (p2B_.x + p3B_.x); \
    float base1B_ = (p0B_.y + p1B_.y) + (p2B_.y + p3B_.y); \
    float d00A_ = vv0A - base0A_; \
    float d01A_ = vv1A - base1A_; \
    float d00B_ = vv0B - base0B_; \
    float d01B_ = vv1B - base1B_; \
    float x0A_ = d00A_ * d00A_, x1A_ = d00A_ * d01A_; \
    float x2A_ = d01A_ * d01A_, x3A_ = knl2A_ * knl3A_; \
    float x0B_ = d00B_ * d00B_, x1B_ = d00B_ * d01B_; \
    float x2B_ = d01B_ * d01B_, x3B_ = knl2B_ * knl3B_; \
    wsum8(x0A_, x1A_, x2A_, x3A_, x0B_, x1B_, x2B_, x3B_); \
    bool g0A_ = x0A_ > th0A; \
    float corrA_ = fmaf(2.f * c3A, x1A_, -(c3A * c3A) * x0A_); \
    float e1A_ = g0A_ ? (x2A_ - corrA_) : x2A_; \
    bool g1A_ = e1A_ > th1A; \
    float gd0A_ = g0A_ ? d00A_ : 0.f; \
    float d1A_  = fmaf(-c3A, gd0A_, d01A_); \
    gdpA = gd0A_; \
    gdqA = g1A_ ? d1A_ : 0.f; \
    bool g0B_ = x0B_ > th0B; \
    float corrB_ = fmaf(2.f * c3B, x1B_, -(c3B * c3B) * x0B_); \
    float e1B_ = g0B_ ? (x2B_ - corrB_) : x2B_; \
    bool g1B_ = e1B_ > th1B; \
    float gd0B_ = g0B_ ? d00B_ : 0.f; \
    float d1B_  = fmaf(-c3B, gd0B_, d01B_); \
    gdpB = gd0B_; \
    gdqB = g1B_ ? d1B_ : 0.f; \
    vv0A = vv2A_; vv1A = vv3A_; th0A = th2A_; th1A = th3A_; c3A = x3A_; \
    vv0B = vv2B_; vv1B = vv3B_; th0B = th2B_; th1B = th3B_; c3B = x3B_; \
} while (0)

// 8 dual chunks covering one 16-row buffer (steps 16c .. 16c+15, both batches)
#define BUF8AB(CB, NB, TP) \
    CHUNK2AB(U,V,S,T,(CB)+2*128, (CB)+3*128, (TP)+2, (TP)+3, 0); \
    CHUNK2AB(S,T,U,V,(CB)+4*128, (CB)+5*128, (TP)+4, (TP)+5, 1); \
    CHUNK2AB(U,V,S,T,(CB)+6*128, (CB)+7*128, (TP)+6, (TP)+7, 0); \
    CHUNK2AB(S,T,U,V,(CB)+8*128, (CB)+9*128, (TP)+8, (TP)+9, 1); \
    CHUNK2AB(U,V,S,T,(CB)+10*128,(CB)+11*128,(TP)+10,(TP)+11,0); \
    CHUNK2AB(S,T,U,V,(CB)+12*128,(CB)+13*128,(TP)+12,(TP)+13,1); \
    CHUNK2AB(U,V,S,T,(CB)+14*128,(CB)+15*128,(TP)+14,(TP)+15,0); \
    CHUNK2AB(S,T,U,V,(NB)+0*128, (NB)+1*128, (TP)+16,(TP)+17,1);

// async copy: 1024 B contiguous global -> contiguous LDS (one inst)
__device__ __forceinline__ void gl2lds_1k(const float* g, float* l, int lane) {
    __builtin_amdgcn_global_load_lds(
        (const __attribute__((address_space(1))) void*)(g + lane * 4),
        (__attribute__((address_space(3))) void*)l, 16, 0, 0);
}

// wave w stages rows 4w..4w+3 of a 16-row buffer (2 KB = 2 insts)
__device__ __forceinline__ void prefetch_quarter(const float* g, float* l,
                                                 int lane, int wid) {
#pragma unroll
    for (int j = 0; j < 2; ++j)
        gl2lds_1k(g + wid * 512 + j * 256, l + wid * 512 + j * 256, lane);
}

__global__ __launch_bounds__(256, 1)
void scan_kernel(const float* __restrict__ knv,
                 const float* __restrict__ vthr,
                 const float* __restrict__ qbuf,
                 const float* __restrict__ rp_W, const float* __restrict__ rp_b,
                 const float* __restrict__ out_W, const float* __restrict__ out_b,
                 float* __restrict__ out)
{
    const int p    = blockIdx.x;       // batch pair
    const int bA   = 2 * p;
    const int bB   = 2 * p + 1;
    const int tid  = threadIdx.x;
    const int lane = tid & 63;
    const int wid  = tid >> 6;
    const float* knvbA = knv  + (size_t)bA * 1024 * 128;
    const float* knvbB = knv  + (size_t)bB * 1024 * 128;
    const float* thrbA = vthr + (size_t)bA * 1024;

    // ONE array -> bufB = bufA + 6144 guaranteed (the r15 bug)
    __shared__ __align__(16) float bufAB[2 * 6144];   // 48 KB
    __shared__ __align__(16) float pexA[2][4][128];   // 4 KB
    __shared__ __align__(16) float pexB[2][4][128];   // 4 KB
    __shared__ float sh[64];
    float* bufA = bufAB;
    float* bufB = bufAB + 6144;

    // per-batch M quarters and kn quarter-set banks
    v4f mA0={0,0,0,0}, mA1={0,0,0,0}, mA2={0,0,0,0}, mA3={0,0,0,0};
    v4f mB0={0,0,0,0}, mB1={0,0,0,0}, mB2={0,0,0,0}, mB3={0,0,0,0};
    v4f SA0,SA1,SA2,SA3, TA0,TA1,TA2,TA3, UA0,UA1,UA2,UA3, VA0,VA1,VA2,VA3;
    v4f SB0,SB1,SB2,SB3, TB0,TB1,TB2,TB3, UB0,UB1,UB2,UB3, VB0,VB1,VB2,VB3;

    // staging: both batches' buffers 0,1,2 (4 insts per slot: 2A + 2B)
    prefetch_quarter(knvbA,        bufA,        lane, wid);
    prefetch_quarter(knvbB,        bufB,        lane, wid);
    prefetch_quarter(knvbA + 2048, bufA + 2048, lane, wid);
    prefetch_quarter(knvbB + 2048, bufB + 2048, lane, wid);
    prefetch_quarter(knvbA + 4096, bufA + 4096, lane, wid);
    prefetch_quarter(knvbB + 4096, bufB + 4096, lane, wid);

    // zero pexA+pexB: 2048 floats / 256 threads = 2 float4 each
    {
        float4 z4 = make_float4(0.f, 0.f, 0.f, 0.f);
        ((float4*)pexA)[tid] = z4;            // pexA is 1024 floats = 256 f4
        ((float4*)pexB)[tid] = z4;
    }

    // slots 0,1 of both batches resident (slot 2's 4 insts in flight)
    asm volatile("s_waitcnt vmcnt(4) lgkmcnt(0)\n\ts_barrier" ::: "memory");

    // prologue per batch: S,T <- rows 0,1; U,V = zeros (gd=0 no-op sources)
    LOADK4(SA, bufA);
    LOADK4(TA, bufA + 128);
    LOADK4(SB, bufB);
    LOADK4(TB, bufB + 128);
    {
        v4f z_ = {0.f, 0.f, 0.f, 0.f};
        UA0=z_;UA1=z_;UA2=z_;UA3=z_; VA0=z_;VA1=z_;VA2=z_;VA3=z_;
        UB0=z_;UB1=z_;UB2=z_;UB3=z_; VB0=z_;VB1=z_;VB2=z_;VB3=z_;
    }
    float vv0A = bufA[64 + lane];
    float vv1A = bufA[192 + lane];
    float vv0B = bufB[64 + lane];
    float vv1B = bufB[192 + lane];
    float th0A = thrbA[0];
    float th1A = thrbA[1];
    float th0B = thrbA[1024];
    float th1B = thrbA[1025];
    float c3A  = wave_sum64(bufA[lane] * bufA[128 + lane]);
    float c3B  = wave_sum64(bufB[lane] * bufB[128 + lane]);
    float gdpA = 0.f, gdqA = 0.f, gdpB = 0.f, gdqB = 0.f;

#pragma unroll 1
    for (int c = 0; c < 62; ++c) {
        // outstanding <= 8; vmcnt(4) -> buffer c+1 of BOTH batches resident
        asm volatile("s_waitcnt vmcnt(4)" ::: "memory");
        const float* cb = bufA + (c % 3) * 2048;
        const float* nb = bufA + ((c + 1) % 3) * 2048;
        const float* tp = thrbA + c * 16;
        BUF8AB(cb, nb, tp)
        if (c <= 60) {
            prefetch_quarter(knvbA + (size_t)(c + 3) * 2048,
                             bufA + (c % 3) * 2048, lane, wid);
            prefetch_quarter(knvbB + (size_t)(c + 3) * 2048,
                             bufB + (c % 3) * 2048, lane, wid);
        }
    }
    asm volatile("s_waitcnt vmcnt(0)" ::: "memory");
    asm volatile("s_barrier" ::: "memory");   // buffers 62,63 fully staged
    {   // buffer 62 (slot 2), lookahead into buffer 63 (slot 0)
        const float* cb = bufA + 2 * 2048;
        const float* nb = bufA;
        const float* tp = thrbA + 62 * 16;
        BUF8AB(cb, nb, tp)
    }
    {   // buffer 63 (slot 0): steps 1008..1023 (1023 = dummy); NB dummy slot 1
        const float* cb = bufA;
        const float* nb = bufA + 2048;
        const float* tp = thrbA + 63 * 16;
        BUF8AB(cb, nb, tp)
    }
    // final updates: M_{1022} = M_{1021} + gd_{1022} kn_{1022}^T  (per batch;
    // U banks hold row 1022 = the last chunk's DOT source)
    UPD4M(mA, UA, gdpA);
    UPD4M(mB, UB, gdpB);

    // ---- output heads (batch A then batch B); wid 0 finishes each ----
    {
        const v4f* qqA = (const v4f*)(qbuf + bA * 64);
        const int w4i = 4 * wid;
        v4f aqA = F4(mA0, qqA[w4i+0], F4(mA1, qqA[w4i+1],
                  F4(mA2, qqA[w4i+2],  mA3 * qqA[w4i+3])));
        float vqA_own = (aqA.x + aqA.y) + (aqA.z + aqA.w);
        const v4f* qqB = (const v4f*)(qbuf + bB * 64);
        v4f aqB = F4(mB0, qqB[w4i+0], F4(mB1, qqB[w4i+1],
                  F4(mB2, qqB[w4i+2],  mB3 * qqB[w4i+3])));
        float vqB_own = (aqB.x + aqB.y) + (aqB.z + aqB.w);
        pexA[0][wid][lane] = vqA_own;
        pexB[0][wid][lane] = vqB_own;
        asm volatile("s_waitcnt lgkmcnt(0)\n\ts_barrier" ::: "memory");

        if (wid == 0) {
            // batch A
            float vqA = (pexA[0][0][lane] + pexA[0][1][lane])
                      + (pexA[0][2][lane] + pexA[0][3][lane]);
            sh[lane] = vqA;
            asm volatile("s_waitcnt lgkmcnt(0)" ::: "memory");
            float rA = rp_b[lane];
#pragma unroll
            for (int ii = 0; ii < 64; ++ii) rA = fmaf(sh[ii], rp_W[ii * 64 + lane], rA);
            asm volatile("s_waitcnt lgkmcnt(0)" ::: "memory");
            sh[lane] = rA;
            asm volatile("s_waitcnt lgkmcnt(0)" ::: "memory");
            float oA = out_b[lane];
#pragma unroll
            for (int ii = 0; ii < 64; ++ii) oA = fmaf(sh[ii], out_W[ii * 64 + lane], oA);
            out[bA * 64 + lane] = oA;
            // batch B
            asm volatile("s_waitcnt lgkmcnt(0)" ::: "memory");
            float vqB = (pexB[0][0][lane] + pexB[0][1][lane])
                      + (pexB[0][2][lane] + pexB[0][3][lane]);
            sh[lane] = vqB;
            asm volatile("s_waitcnt lgkmcnt(0)" ::: "memory");
            float rB = rp_b[lane];
#pragma unroll
            for (int ii = 0; ii < 64; ++ii) rB = fmaf(sh[ii], rp_W[ii * 64 + lane], rB);
            asm volatile("s_waitcnt lgkmcnt(0)" ::: "memory");
            sh[lane] = rB;
            asm volatile("s_waitcnt lgkmcnt(0)" ::: "memory");
            float oB = out_b[lane];
#pragma unroll
            for (int ii = 0; ii < 64; ++ii) oB = fmaf(sh[ii], out_W[ii * 64 + lane], oB);
            out[bB * 64 + lane] = oB;
        }
    }
}

// ---------------------------------------------------------------------------
// Launch. Workspace (fp32): knv[64][1024][128] (33.55 MB, t=1023 row unused) |
// vthr[64][1024] (262 KB) | qbuf[64][64]. Total ~33.9 MB.
// ---------------------------------------------------------------------------
extern "C" void kernel_launch(void* const* d_in, const int* in_sizes, int n_in,
                              void* d_out, int out_size, void* d_ws, size_t ws_size,
                              hipStream_t stream)
{
    const int*   seq   = (const int*)  d_in[0];
    const float* embed = (const float*)d_in[1];
    const float* ffW1  = (const float*)d_in[2];
    const float* ffb1  = (const float*)d_in[3];
    const float* ffW2  = (const float*)d_in[4];
    const float* ffb2  = (const float*)d_in[5];
    const float* lng   = (const float*)d_in[6];
    const float* lnb   = (const float*)d_in[7];
    const float* kpW   = (const float*)d_in[8];
    const float* vpW   = (const float*)d_in[9];
    const float* qpW   = (const float*)d_in[10];
    const float* rpW   = (const float*)d_in[11];
    const float* rpb   = (const float*)d_in[12];
    const float* outW  = (const float*)d_in[13];
    const float* outb  = (const float*)d_in[14];
    float* out = (float*)d_out;

    float* knv  = (float*)d_ws;
    float* vthr = knv  + (size_t)64 * 1024 * 128;
    float* qbuf = vthr + (size_t)64 * 1024;

    token_kernel<<<2048, 256, 0, stream>>>(seq, embed, ffW1, ffb1, ffW2, ffb2,
                                           lng, lnb, kpW, vpW, qpW,
                                           knv, vthr, qbuf);
    scan_kernel<<<32, 256, 0, stream>>>(knv, vthr, qbuf,
                                        rpW, rpb, outW, outb, out);
}

// Round 17
// 365.082 us; speedup vs baseline: 1.3946x; 1.3946x over previous
//
#include <hip/hip_runtime.h>
#include <hip/hip_bf16.h>
#include <math.h>

// Problem constants (reference: B=64, L=1024, H=64, VOCAB=64)
#define BB 64
#define LL 1024
#define HH 64

typedef float v4f __attribute__((ext_vector_type(4)));
#define F4 __builtin_elementwise_fma

// ---------------------------------------------------------------------------
// Kernel 1: per-token phase (v1, best measured).
// block = 256 threads (4 waves), 32 tokens/block, grid = 65536/32 = 2048.
// Computes hn = LN(h + FF(h)), then writes packed stream knv[b][t] =
// [kn(64) | v(64)] (t<1023) plus vthr[b][t] = 0.16*||v||^2 (SQUARED threshold,
// consumed by the scan's sqrt-free gate), or q (t==1023).
// ---------------------------------------------------------------------------
__global__ __launch_bounds__(256, 1)
void token_kernel(const int* __restrict__ seq,
                  const float* __restrict__ embed_W,
                  const float* __restrict__ ff_W1, const float* __restrict__ ff_b1,
                  const float* __restrict__ ff_W2, const float* __restrict__ ff_b2,
                  const float* __restrict__ ln_g, const float* __restrict__ ln_b,
                  const float* __restrict__ kp_W, const float* __restrict__ vp_W,
                  const float* __restrict__ qp_W,
                  float* __restrict__ knv, float* __restrict__ vthr,
                  float* __restrict__ qbuf)
{
    __shared__ __align__(16) float h_s[32][64];    // 8 KB
    __shared__ __align__(16) float t1_s[32][128];  // 16 KB
    __shared__ __align__(16) float hn_s[32][64];   // 8 KB

    const int tid  = threadIdx.x;
    const int tok0 = blockIdx.x * 32;

    // ---- Stage A: embedding gather into LDS ----
#pragma unroll
    for (int k = 0; k < 8; ++k) {
        int e   = k * 256 + tid;
        int tok = e >> 6, i = e & 63;
        int s   = seq[tok0 + tok];
        h_s[tok][i] = embed_W[s * 64 + i];
    }
    __syncthreads();

    // ---- Stage B: FF1 (64 -> 128, ReLU) ----
    {
        const int j = tid & 127;
        const int g = tid >> 7;
        float w1c[64];
#pragma unroll
        for (int ii = 0; ii < 64; ++ii) w1c[ii] = ff_W1[ii * 128 + j];
        const float b1j = ff_b1[j];
#pragma unroll
        for (int tk = 0; tk < 16; ++tk) {
            const int tok = g * 16 + tk;
            const float4* h4 = (const float4*)h_s[tok];
            float a0 = b1j, a1 = 0.f, a2 = 0.f, a3 = 0.f;
#pragma unroll
            for (int w = 0; w < 16; ++w) {
                float4 hv = h4[w];
                a0 = fmaf(hv.x, w1c[4*w+0], a0);
                a1 = fmaf(hv.y, w1c[4*w+1], a1);
                a2 = fmaf(hv.z, w1c[4*w+2], a2);
                a3 = fmaf(hv.w, w1c[4*w+3], a3);
            }
            t1_s[tok][j] = fmaxf((a0 + a1) + (a2 + a3), 0.f);
        }
    }
    __syncthreads();

    // ---- Stage C: FF2 (128 -> 64) + residual + LayerNorm (w2 in 2 halves) ----
    {
        const int i  = tid & 63;
        const int w4 = tid >> 6;
        const float b2i = ff_b2[i];
        const float gi  = ln_g[i];
        const float bi  = ln_b[i];
        float accf[8];
#pragma unroll
        for (int tk = 0; tk < 8; ++tk) accf[tk] = b2i;
#pragma unroll
        for (int h = 0; h < 2; ++h) {
            float w2c[64];
#pragma unroll
            for (int jj = 0; jj < 64; ++jj) w2c[jj] = ff_W2[(h*64 + jj) * 64 + i];
#pragma unroll
            for (int tk = 0; tk < 8; ++tk) {
                const int tok = w4 * 8 + tk;
                const float4* t4 = (const float4*)&t1_s[tok][h*64];
                float a0 = 0.f, a1 = 0.f, a2 = 0.f, a3 = 0.f;
#pragma unroll
                for (int w = 0; w < 16; ++w) {
                    float4 tv = t4[w];
                    a0 = fmaf(tv.x, w2c[4*w+0], a0);
                    a1 = fmaf(tv.y, w2c[4*w+1], a1);
                    a2 = fmaf(tv.z, w2c[4*w+2], a2);
                    a3 = fmaf(tv.w, w2c[4*w+3], a3);
                }
                accf[tk] += (a0 + a1) + (a2 + a3);
            }
        }
#pragma unroll
        for (int tk = 0; tk < 8; ++tk) {
            const int tok = w4 * 8 + tk;
            float x = h_s[tok][i] + accf[tk];
            float s = x;
#pragma unroll
            for (int m = 32; m > 0; m >>= 1) s += __shfl_xor(s, m);
            float mu = s * (1.f / 64.f);
            float d  = x - mu;
            float s2 = d * d;
#pragma unroll
            for (int m = 32; m > 0; m >>= 1) s2 += __shfl_xor(s2, m);
            float var = s2 * (1.f / 64.f);
            hn_s[tok][i] = d / sqrtf(var + 1e-5f) * gi + bi;
        }
    }
    __syncthreads();

    // ---- Stage D: kn/v into packed stream (t<1023) OR q (t==1023) ----
    {
        const int i  = tid & 63;
        const int w4 = tid >> 6;
        float kc[64], vc[64];
#pragma unroll
        for (int ii = 0; ii < 64; ++ii) {
            kc[ii] = kp_W[ii * 64 + i];
            vc[ii] = vp_W[ii * 64 + i];
        }
#pragma unroll
        for (int tk = 0; tk < 8; ++tk) {
            const int tok = w4 * 8 + tk;
            const int tg  = tok0 + tok;
            const int b   = tg >> 10;
            const int t   = tg & 1023;
            const float4* hn4 = (const float4*)hn_s[tok];
            if (t < 1023) {
                float ka0=0.f,ka1=0.f,ka2=0.f,ka3=0.f;
                float va0=0.f,va1=0.f,va2=0.f,va3=0.f;
#pragma unroll
                for (int w = 0; w < 16; ++w) {
                    float4 hv = hn4[w];
                    ka0 = fmaf(hv.x, kc[4*w+0], ka0);
                    ka1 = fmaf(hv.y, kc[4*w+1], ka1);
                    ka2 = fmaf(hv.z, kc[4*w+2], ka2);
                    ka3 = fmaf(hv.w, kc[4*w+3], ka3);
                    va0 = fmaf(hv.x, vc[4*w+0], va0);
                    va1 = fmaf(hv.y, vc[4*w+1], va1);
                    va2 = fmaf(hv.z, vc[4*w+2], va2);
                    va3 = fmaf(hv.w, vc[4*w+3], va3);
                }
                float ka = (ka0 + ka1) + (ka2 + ka3);
                float va = (va0 + va1) + (va2 + va3);
                float kn2 = ka * ka, vn2 = va * va;
#pragma unroll
                for (int m = 32; m > 0; m >>= 1) {
                    kn2 += __shfl_xor(kn2, m);
                    vn2 += __shfl_xor(vn2, m);
                }
                float knorm = fmaxf(sqrtf(kn2), 1e-12f);
                size_t row = ((size_t)b * 1024 + t) * 128;
                knv[row + i]      = ka / knorm;
                knv[row + 64 + i] = va;
                if (i == 0) vthr[b * 1024 + t] = 0.16f * vn2;   // SQUARED threshold
            } else {
                float qa0=0.f,qa1=0.f,qa2=0.f,qa3=0.f;
#pragma unroll
                for (int w = 0; w < 16; ++w) {
                    float4 hv = hn4[w];
                    qa0 = fmaf(hv.x, qp_W[(4*w+0)*64 + i], qa0);
                    qa1 = fmaf(hv.y, qp_W[(4*w+1)*64 + i], qa1);
                    qa2 = fmaf(hv.z, qp_W[(4*w+2)*64 + i], qa2);
                    qa3 = fmaf(hv.w, qp_W[(4*w+3)*64 + i], qa3);
                }
                qbuf[b * 64 + i] = (qa0 + qa1) + (qa2 + qa3);
            }
        }
    }
}

// ---------------------------------------------------------------------------
// Kernel 2: sequential fast-weight scan + output head.
// BEST MEASURED (r8/r10, 210.7-211.4 us): G=2 chunks, 4-wave column split.
// Wave w owns columns [16w,16w+16). Per chunk each wave does quarter-DOTs
// and quarter-UPDs; reduce + gate algebra run redundantly (bit-identical
// across waves: fixed trees). One barrier per two steps; gate uses the exact
// pair expansion e1 = S0 - g0(2 c3 S1 - c3^2 S2).
// grid = 64 (one block/batch), block = 256 (4 waves).
// ---------------------------------------------------------------------------

template<int CTRL>
__device__ __forceinline__ float dppadd(float x) {
    int y = __builtin_amdgcn_update_dpp(0, __float_as_int(x), CTRL, 0xF, 0xF, true);
    return x + __int_as_float(y);
}

__device__ __forceinline__ float bcast63(float x) {
    return __int_as_float(__builtin_amdgcn_readlane(__float_as_int(x), 63));
}

// full-wave (64 lane) sum, result broadcast (prologue use)
__device__ __forceinline__ float wave_sum64(float x) {
    x = dppadd<0x111>(x); x = dppadd<0x112>(x);
    x = dppadd<0x114>(x); x = dppadd<0x118>(x);
    x = dppadd<0x142>(x); x = dppadd<0x143>(x);
    return bcast63(x);
}

// four independent wave sums, DPP levels interleaved (latency amortized)
__device__ __forceinline__ void wsum4(float& a, float& b, float& c, float& d) {
    a = dppadd<0x111>(a); b = dppadd<0x111>(b); c = dppadd<0x111>(c); d = dppadd<0x111>(d);
    a = dppadd<0x112>(a); b = dppadd<0x112>(b); c = dppadd<0x112>(c); d = dppadd<0x112>(d);
    a = dppadd<0x114>(a); b = dppadd<0x114>(b); c = dppadd<0x114>(c); d = dppadd<0x114>(d);
    a = dppadd<0x118>(a); b = dppadd<0x118>(b); c = dppadd<0x118>(c); d = dppadd<0x118>(d);
    a = dppadd<0x142>(a); b = dppadd<0x142>(b); c = dppadd<0x142>(c); d = dppadd<0x142>(d);
    a = dppadd<0x143>(a); b = dppadd<0x143>(b); c = dppadd<0x143>(c); d = dppadd<0x143>(d);
    a = bcast63(a); b = bcast63(b); c = bcast63(c); d = bcast63(d);
}

// load this wave's quarter of a kn row into quarter-set P (4 x ds_read_b128)
#define LOADK4(P, ROW) do { \
    const float* r_ = (ROW) + (wid << 4); \
    P##0 = *(const v4f*)(r_ + 0);  P##1 = *(const v4f*)(r_ + 4); \
    P##2 = *(const v4f*)(r_ + 8);  P##3 = *(const v4f*)(r_ + 12); \
} while (0)

// M(quarter) += G * P(quarter)   (branchless; G==0 exact no-op on finite P)
#define UPD4(P, G) do { \
    v4f gv_ = {G, G, G, G}; \
    m0 = F4(gv_, P##0, m0); m1 = F4(gv_, P##1, m1); \
    m2 = F4(gv_, P##2, m2); m3 = F4(gv_, P##3, m3); \
} while (0)

// One chunk u (steps 2u, 2u+1).
#define CHUNK2(UP, UQ, XR, XS, ROW2, ROW3, TH2P, TH3P, PAR) do { \
    UPD4(UP, gdp); \
    UPD4(UQ, gdq); \
    v4f q_ = F4(m0, XR##0, F4(m1, XR##1, F4(m2, XR##2, m3 * XR##3))); \
    float own0_ = (q_.x + q_.y) + (q_.z + q_.w); \
    v4f r_ = F4(m0, XS##0, F4(m1, XS##1, F4(m2, XS##2, m3 * XS##3))); \
    float own1_ = (r_.x + r_.y) + (r_.z + r_.w); \
    ((float2*)pex[PAR][wid])[lane] = make_float2(own0_, own1_); \
    asm volatile("s_waitcnt lgkmcnt(0)\n\ts_barrier" ::: "memory"); \
    float2 p0_ = ((const float2*)pex[PAR][0])[lane]; \
    float2 p1_ = ((const float2*)pex[PAR][1])[lane]; \
    float2 p2_ = ((const float2*)pex[PAR][2])[lane]; \
    float2 p3_ = ((const float2*)pex[PAR][3])[lane]; \
    float knl2_ = (ROW2)[lane]; \
    float knl3_ = (ROW3)[lane]; \
    float vv2_  = (ROW2)[64 + lane]; \
    float vv3_  = (ROW3)[64 + lane]; \
    float th2_  = *(TH2P); \
    float th3_  = *(TH3P); \
    LOADK4(UP, ROW2); \
    LOADK4(UQ, ROW3); \
    float base0_ = (p0_.x + p1_.x) + (p2_.x + p3_.x); \
    float base1_ = (p0_.y + p1_.y) + (p2_.y + p3_.y); \
    float d00_ = vv0 - base0_; \
    float d01_ = vv1 - base1_; \
    float x0_ = d00_ * d00_, x1_ = d00_ * d01_; \
    float x2_ = d01_ * d01_, x3_ = knl2_ * knl3_; \
    wsum4(x0_, x1_, x2_, x3_); \
    bool g0_ = x0_ > th0; \
    float corr_ = fmaf(2.f * c3, x1_, -(c3 * c3) * x0_); \
    float e1_ = g0_ ? (x2_ - corr_) : x2_; \
    bool g1_ = e1_ > th1; \
    float gd0_ = g0_ ? d00_ : 0.f; \
    float d1_  = fmaf(-c3, gd0_, d01_); \
    gdp = gd0_; \
    gdq = g1_ ? d1_ : 0.f; \
    vv0 = vv2_; vv1 = vv3_; th0 = th2_; th1 = th3_; c3 = x3_; \
} while (0)

// 8 chunks covering one 16-row buffer (steps 16c .. 16c+15).
#define BUF8(CB, NB, TP) \
    CHUNK2(U,V,S,T,(CB)+2*128, (CB)+3*128, (TP)+2, (TP)+3, 0); \
    CHUNK2(S,T,U,V,(CB)+4*128, (CB)+5*128, (TP)+4, (TP)+5, 1); \
    CHUNK2(U,V,S,T,(CB)+6*128, (CB)+7*128, (TP)+6, (TP)+7, 0); \
    CHUNK2(S,T,U,V,(CB)+8*128, (CB)+9*128, (TP)+8, (TP)+9, 1); \
    CHUNK2(U,V,S,T,(CB)+10*128,(CB)+11*128,(TP)+10,(TP)+11,0); \
    CHUNK2(S,T,U,V,(CB)+12*128,(CB)+13*128,(TP)+12,(TP)+13,1); \
    CHUNK2(U,V,S,T,(CB)+14*128,(CB)+15*128,(TP)+14,(TP)+15,0); \
    CHUNK2(S,T,U,V,(NB)+0*128, (NB)+1*128, (TP)+16,(TP)+17,1);

// async copy: 1024 B contiguous global -> contiguous LDS (one inst)
__device__ __forceinline__ void gl2lds_1k(const float* g, float* l, int lane) {
    __builtin_amdgcn_global_load_lds(
        (const __attribute__((address_space(1))) void*)(g + lane * 4),
        (__attribute__((address_space(3))) void*)l, 16, 0, 0);
}

// wave w stages rows 4w..4w+3 of a 16-row buffer (2 KB = 2 insts)
__device__ __forceinline__ void prefetch_quarter(const float* g, float* l,
                                                 int lane, int wid) {
#pragma unroll
    for (int j = 0; j < 2; ++j)
        gl2lds_1k(g + wid * 512 + j * 256, l + wid * 512 + j * 256, lane);
}

__global__ __launch_bounds__(256, 1)
void scan_kernel(const float* __restrict__ knv,
                 const float* __restrict__ vthr,
                 const float* __restrict__ qbuf,
                 const float* __restrict__ rp_W, const float* __restrict__ rp_b,
                 const float* __restrict__ out_W, const float* __restrict__ out_b,
                 float* __restrict__ out)
{
    const int b    = blockIdx.x;
    const int tid  = threadIdx.x;
    const int lane = tid & 63;
    const int wid  = tid >> 6;
    const float* knvb = knv  + (size_t)b * 1024 * 128;
    const float* thrb = vthr + (size_t)b * 1024;

    __shared__ __align__(16) float thr_s[1040];      // th^2 per step
    __shared__ __align__(16) float buf[3 * 2048];    // 3 x 8 KB buffers
    __shared__ __align__(16) float pex[2][4][128];   // [parity][wave][lane*2]
    __shared__ float sh[64];

    // M quarter: columns [16*wid, 16*wid+16) of lane's row (4 v4f)
    v4f m0={0,0,0,0}, m1={0,0,0,0}, m2={0,0,0,0}, m3={0,0,0,0};
    // four kn quarter-sets; roles alternate per chunk parity
    v4f S0,S1,S2,S3;
    v4f T0,T1,T2,T3;
    v4f U0,U1,U2,U3;
    v4f V0,V1,V2,V3;

    // staging: wave 0 also loads thr (4 insts); each wave 2 insts/buffer
    if (wid == 0) {
#pragma unroll
        for (int w = 0; w < 4; ++w) gl2lds_1k(thrb + w * 256, thr_s + w * 256, lane);
    }
    prefetch_quarter(knvb,        buf,        lane, wid);
    prefetch_quarter(knvb + 2048, buf + 2048, lane, wid);
    prefetch_quarter(knvb + 4096, buf + 4096, lane, wid);

    // zero pex: 1024 floats / 256 threads = 1 float4 each
    {
        float4 z4 = make_float4(0.f, 0.f, 0.f, 0.f);
        ((float4*)pex)[tid] = z4;
    }

    // thr + buffers 0,1 resident own-wave (buffer 2 = 2 insts in flight);
    // barrier makes all waves' quarters visible.
    asm volatile("s_waitcnt vmcnt(2) lgkmcnt(0)\n\ts_barrier" ::: "memory");

    // prologue: chunk 0 expects S=kn_0, T=kn_1, U=V = kn_{-2,-1} = 0
    LOADK4(S, buf);
    LOADK4(T, buf + 128);
    {
        v4f z_ = {0.f, 0.f, 0.f, 0.f};
        U0=z_;U1=z_;U2=z_;U3=z_;
        V0=z_;V1=z_;V2=z_;V3=z_;
    }
    float vv0 = buf[64 + lane];          // v_0[lane]
    float vv1 = buf[192 + lane];         // v_1[lane]
    float th0 = thr_s[0];
    float th1 = thr_s[1];
    float c3  = wave_sum64(buf[lane] * buf[128 + lane]);   // kn_0 . kn_1
    float gdp = 0.f, gdq = 0.f;

#pragma unroll 1
    for (int c = 0; c < 62; ++c) {
        // own outstanding <= 4 (buffers c+1, c+2); vmcnt(2) -> buffer c+1
        // resident own-wave; chunk barriers give cross-wave visibility.
        asm volatile("s_waitcnt vmcnt(2)" ::: "memory");
        const float* cb = buf + (c % 3) * 2048;
        const float* nb = buf + ((c + 1) % 3) * 2048;
        const float* tp = thr_s + c * 16;
        BUF8(cb, nb, tp)
        if (c <= 60)
            prefetch_quarter(knvb + (size_t)(c + 3) * 2048,
                             buf + (c % 3) * 2048, lane, wid);
    }
    asm volatile("s_waitcnt vmcnt(0)" ::: "memory");
    asm volatile("s_barrier" ::: "memory");   // all waves' buffers 62,63 staged
    {   // buffer 62 (slot 2), lookahead into buffer 63 (slot 0)
        const float* cb = buf + 2 * 2048;
        const float* nb = buf;
        const float* tp = thr_s + 62 * 16;
        BUF8(cb, nb, tp)
    }
    {   // buffer 63 (slot 0): steps 1008..1023 (1023 = dummy); NB dummy slot 1
        const float* cb = buf;
        const float* nb = buf + 2048;
        const float* tp = thr_s + 63 * 16;
        BUF8(cb, nb, tp)
    }
    // final update: M_{1022} = M_{1021} + gd_{1022} kn_{1022}^T
    // (gdp = gd_{1022}; U holds kn_{1022}: DOT source of the last chunk)
    UPD4(U, gdp);

    // ---- output head: vq = M q (quarter + exchange), wave 0 finishes ----
    {
        const v4f* qq = (const v4f*)(qbuf + b * 64);
        const int w4i = 4 * wid;
        v4f aq = F4(m0, qq[w4i+0], F4(m1, qq[w4i+1],
                 F4(m2, qq[w4i+2],  m3 * qq[w4i+3])));
        float vq_own = (aq.x + aq.y) + (aq.z + aq.w);
        pex[0][wid][lane] = vq_own;
        asm volatile("s_waitcnt lgkmcnt(0)\n\ts_barrier" ::: "memory");

        if (wid == 0) {
            float vq = (pex[0][0][lane] + pex[0][1][lane])
                     + (pex[0][2][lane] + pex[0][3][lane]);
            sh[lane] = vq;
            asm volatile("s_waitcnt lgkmcnt(0)" ::: "memory");
            float r = rp_b[lane];
#pragma unroll
            for (int ii = 0; ii < 64; ++ii) r = fmaf(sh[ii], rp_W[ii * 64 + lane], r);
            asm volatile("s_waitcnt lgkmcnt(0)" ::: "memory");
            sh[lane] = r;
            asm volatile("s_waitcnt lgkmcnt(0)" ::: "memory");
            float o = out_b[lane];
#pragma unroll
            for (int ii = 0; ii < 64; ++ii) o = fmaf(sh[ii], out_W[ii * 64 + lane], o);
            out[b * 64 + lane] = o;
        }
    }
}

// ---------------------------------------------------------------------------
// Launch. Workspace (fp32): knv[64][1024][128] (33.55 MB, t=1023 row unused) |
// vthr[64][1024] (262 KB) | qbuf[64][64]. Total ~33.9 MB.
// ---------------------------------------------------------------------------
extern "C" void kernel_launch(void* const* d_in, const int* in_sizes, int n_in,
                              void* d_out, int out_size, void* d_ws, size_t ws_size,
                              hipStream_t stream)
{
    const int*   seq   = (const int*)  d_in[0];
    const float* embed = (const float*)d_in[1];
    const float* ffW1  = (const float*)d_in[2];
    const float* ffb1  = (const float*)d_in[3];
    const float* ffW2  = (const float*)d_in[4];
    const float* ffb2  = (const float*)d_in[5];
    const float* lng   = (const float*)d_in[6];
    const float* lnb   = (const float*)d_in[7];
    const float* kpW   = (const float*)d_in[8];
    const float* vpW   = (const float*)d_in[9];
    const float* qpW   = (const float*)d_in[10];
    const float* rpW   = (const float*)d_in[11];
    const float* rpb   = (const float*)d_in[12];
    const float* outW  = (const float*)d_in[13];
    const float* outb  = (const float*)d_in[14];
    float* out = (float*)d_out;

    float* knv  = (float*)d_ws;
    float* vthr = knv  + (size_t)64 * 1024 * 128;
    float* qbuf = vthr + (size_t)64 * 1024;

    token_kernel<<<2048, 256, 0, stream>>>(seq, embed, ffW1, ffb1, ffW2, ffb2,
                                           lng, lnb, kpW, vpW, qpW,
                                           knv, vthr, qbuf);
    scan_kernel<<<64, 256, 0, stream>>>(knv, vthr, qbuf,
                                        rpW, rpb, outW, outb, out);
}